// Round 3
// baseline (454.306 us; speedup 1.0000x reference)
//
#include <hip/hip_runtime.h>
#include <hip/hip_bf16.h>

// Problem dims
#define TT 128
#define BB 64
#define NN 1024
#define ROWS (TT * BB)  // 8192

// ---------------------------------------------------------------------------
// GEMM1: H[r][m] = sum_n X[r][n] * W1[m][n]   (fp32 in, fp64 accumulate)
// Tile: BM=128 x BN=64, KT=32, 256 threads, per-thread 8x4 outputs.
// ---------------------------------------------------------------------------
#define BM 128
#define BN 64
#define KT 32
#define SA 132
#define SB 68

__global__ __launch_bounds__(256) void gemm1_f64(const float* __restrict__ X,
                                                 const float* __restrict__ W1,
                                                 float* __restrict__ H) {
    __shared__ float As[KT][SA];
    __shared__ float Bs[KT][SB];
    const int tid = threadIdx.x;
    const int bm  = blockIdx.y;   // 0..63
    const int bn  = blockIdx.x;   // 0..15
    const int tm  = tid >> 4;     // 0..15 -> 8 rows each
    const int tn  = tid & 15;     // 0..15 -> 4 cols each
    const int lrow = tid >> 3;    // 0..31
    const int lk4  = (tid & 7) << 2;  // 0,4,...,28

    double acc[8][4];
#pragma unroll
    for (int i = 0; i < 8; ++i)
#pragma unroll
        for (int j = 0; j < 4; ++j) acc[i][j] = 0.0;

    for (int kt = 0; kt < NN; kt += KT) {
#pragma unroll
        for (int p = 0; p < 4; ++p) {
            const int m = lrow + p * 32;
            const float4 v = *(const float4*)&X[(size_t)(bm * BM + m) * NN + kt + lk4];
            As[lk4 + 0][m] = v.x; As[lk4 + 1][m] = v.y;
            As[lk4 + 2][m] = v.z; As[lk4 + 3][m] = v.w;
        }
#pragma unroll
        for (int p = 0; p < 2; ++p) {
            const int n = lrow + p * 32;
            const float4 v = *(const float4*)&W1[(size_t)(bn * BN + n) * NN + kt + lk4];
            Bs[lk4 + 0][n] = v.x; Bs[lk4 + 1][n] = v.y;
            Bs[lk4 + 2][n] = v.z; Bs[lk4 + 3][n] = v.w;
        }
        __syncthreads();
#pragma unroll
        for (int k = 0; k < KT; ++k) {
            float a[8], b[4];
            *(float4*)&a[0] = *(const float4*)&As[k][tm * 8];
            *(float4*)&a[4] = *(const float4*)&As[k][tm * 8 + 4];
            *(float4*)&b[0] = *(const float4*)&Bs[k][tn * 4];
#pragma unroll
            for (int i = 0; i < 8; ++i)
#pragma unroll
                for (int j = 0; j < 4; ++j)
                    acc[i][j] = fma((double)a[i], (double)b[j], acc[i][j]);
        }
        __syncthreads();
    }
#pragma unroll
    for (int i = 0; i < 8; ++i) {
        float4 v;
        v.x = (float)acc[i][0]; v.y = (float)acc[i][1];
        v.z = (float)acc[i][2]; v.w = (float)acc[i][3];
        *(float4*)&H[(size_t)(bm * BM + tm * 8 + i) * NN + bn * BN + tn * 4] = v;
    }
}

// ---------------------------------------------------------------------------
// Transpose w2 [m][n] -> w2t [n][m] so sparse GEMM2 reads coalesced rows.
// ---------------------------------------------------------------------------
__global__ __launch_bounds__(256) void transp_k(const float* __restrict__ A,
                                                float* __restrict__ B) {
    __shared__ float tile[32][33];
    const int tx  = threadIdx.x & 31;
    const int ty4 = (threadIdx.x >> 5) * 4;
    const int c0 = blockIdx.x * 32;
    const int r0 = blockIdx.y * 32;
#pragma unroll
    for (int i = 0; i < 4; ++i)
        tile[ty4 + i][tx] = A[(size_t)(r0 + ty4 + i) * NN + c0 + tx];
    __syncthreads();
#pragma unroll
    for (int i = 0; i < 4; ++i)
        B[(size_t)(c0 + ty4 + i) * NN + r0 + tx] = tile[tx][ty4 + i];
}

// ---------------------------------------------------------------------------
// LIF scan: one thread per (b,n), fp64 state, spikes packed to 64-bit masks
// via __ballot. Masks: M[t*1024 + (e>>6)], bit l <-> n = base + l.
// ---------------------------------------------------------------------------
__global__ __launch_bounds__(256) void lif_k(const float* __restrict__ H,
                                             unsigned long long* __restrict__ M) {
    const int e    = blockIdx.x * 256 + threadIdx.x;  // 0..65535  (b*1024+n)
    const int lane = threadIdx.x & 63;
    const int word = e >> 6;                          // 0..1023
    double v = 0.0;

    float buf[8];
#pragma unroll
    for (int i = 0; i < 8; ++i) buf[i] = H[(size_t)i * 65536 + e];

#pragma unroll 8
    for (int t = 0; t < TT; ++t) {
        const float hcur = buf[t & 7];
        if (t + 8 < TT) buf[t & 7] = H[(size_t)(t + 8) * 65536 + e];
        const double hv = v + ((double)hcur - v) * 0.5;  // TAU = 2
        const bool s = (hv >= 1.0);
        const unsigned long long bmask = __ballot(s);
        if (lane == 0) M[(size_t)t * 1024 + word] = bmask;
        v = s ? 0.0 : hv;
    }
}

// ---------------------------------------------------------------------------
// Sparse GEMM2: out[r][:] = sum over active n of w2t[n][:].
// One block per output row (r = t*64+b); bitmask-driven, deterministic
// ascending-n order; fp64 accumulate; fp32 store.
// ---------------------------------------------------------------------------
__global__ __launch_bounds__(256) void spmm2_k(const unsigned long long* __restrict__ M,
                                               const float* __restrict__ W2T,
                                               float* __restrict__ OUT) {
    __shared__ unsigned long long sm[16];
    const int r   = blockIdx.x;   // 0..8191 (= t*64 + b)
    const int tid = threadIdx.x;  // 256 threads, 4 cols each
    if (tid < 16) sm[tid] = M[(size_t)r * 16 + tid];
    __syncthreads();

    double a0 = 0.0, a1 = 0.0, a2 = 0.0, a3 = 0.0;
    for (int w = 0; w < 16; ++w) {
        unsigned long long bits = sm[w];
        while (bits) {
            const int l = __builtin_ctzll(bits);
            bits &= bits - 1;
            const int n = w * 64 + l;
            const float4 wv = *(const float4*)&W2T[(size_t)n * NN + tid * 4];
            a0 += (double)wv.x; a1 += (double)wv.y;
            a2 += (double)wv.z; a3 += (double)wv.w;
        }
    }
    float4 o;
    o.x = (float)a0; o.y = (float)a1; o.z = (float)a2; o.w = (float)a3;
    *(float4*)&OUT[(size_t)r * NN + tid * 4] = o;
}

// ---------------------------------------------------------------------------
extern "C" void kernel_launch(void* const* d_in, const int* in_sizes, int n_in,
                              void* d_out, int out_size, void* d_ws, size_t ws_size,
                              hipStream_t stream) {
    const float* x  = (const float*)d_in[0];   // [128,64,1024] fp32
    const float* w1 = (const float*)d_in[1];   // [1024,1024] fp32
    const float* w2 = (const float*)d_in[2];   // [1024,1024] fp32
    float* out = (float*)d_out;                // fp32 [128,64,1024]

    char* ws = (char*)d_ws;
    float* h   = (float*)ws;                              // 33,554,432 B
    float* w2t = (float*)(ws + 33554432);                 //  4,194,304 B
    unsigned long long* masks =
        (unsigned long long*)(ws + 33554432 + 4194304);   //  1,048,576 B

    gemm1_f64<<<dim3(16, 64), 256, 0, stream>>>(x, w1, h);
    transp_k<<<dim3(32, 32), 256, 0, stream>>>(w2, w2t);
    lif_k<<<256, 256, 0, stream>>>(h, masks);
    spmm2_k<<<8192, 256, 0, stream>>>(masks, w2t, out);
}

// Round 4
// 214.294 us; speedup vs baseline: 2.1200x; 2.1200x over previous
//
#include <hip/hip_runtime.h>
#include <hip/hip_bf16.h>

#define TT 128
#define BB 64
#define NN 1024

typedef __attribute__((ext_vector_type(4))) float f32x4;
typedef __attribute__((ext_vector_type(8))) short bf16x8;

// ---------------------------------------------------------------------------
// bf16 split helpers (RNE via bit trick; residual exact in fp32)
// ---------------------------------------------------------------------------
__device__ __forceinline__ unsigned short bf_hi_rne(float f, float& rem) {
    union { float f; unsigned int u; } c; c.f = f;
    const unsigned int r = c.u + 0x7fffu + ((c.u >> 16) & 1u);
    const unsigned short h = (unsigned short)(r >> 16);
    union { unsigned int u; float f; } b; b.u = ((unsigned int)h) << 16;
    rem = f - b.f;   // exact (Sterbenz-range subtraction)
    return h;
}

// Split fp32 matrix into hi/lo bf16 matrices. 4 elems/thread.
__global__ __launch_bounds__(256) void split_k(const float* __restrict__ A,
                                               unsigned short* __restrict__ Hi,
                                               unsigned short* __restrict__ Lo) {
    const size_t f = ((size_t)blockIdx.x * 256 + threadIdx.x) * 4;
    const float4 v = *(const float4*)(A + f);
    float r, r2;
    ushort4 hi, lo;
    hi.x = bf_hi_rne(v.x, r); lo.x = bf_hi_rne(r, r2);
    hi.y = bf_hi_rne(v.y, r); lo.y = bf_hi_rne(r, r2);
    hi.z = bf_hi_rne(v.z, r); lo.z = bf_hi_rne(r, r2);
    hi.w = bf_hi_rne(v.w, r); lo.w = bf_hi_rne(r, r2);
    *(ushort4*)(Hi + f) = hi;
    *(ushort4*)(Lo + f) = lo;
}

// ---------------------------------------------------------------------------
// GEMM1 via MFMA: H[r][m] = sum_k x[r][k] * w1[m][k], 3-pass split-bf16.
// 128x128 tile, BK=32, 4 waves; global_load_lds(16) staging, swizzled LDS.
// Each wave stages one 8KB buffer; computes a 64x64 sub-tile (4x4 frags).
// ---------------------------------------------------------------------------
__global__ __launch_bounds__(256) void gemm1_mfma(
    const unsigned short* __restrict__ A0g, const unsigned short* __restrict__ A1g,
    const unsigned short* __restrict__ B0g, const unsigned short* __restrict__ B1g,
    float* __restrict__ H) {
    __shared__ unsigned short lds[4][128 * 32];  // A0,A1,B0,B1 tiles: 8 KB each

    const int tid  = threadIdx.x;
    const int wave = tid >> 6;
    const int lane = tid & 63;
    const int bm = blockIdx.y, bn = blockIdx.x;
    const int wm = (wave >> 1) * 64, wn = (wave & 1) * 64;

    f32x4 acc[4][4];
#pragma unroll
    for (int i = 0; i < 4; ++i)
#pragma unroll
        for (int j = 0; j < 4; ++j) acc[i][j] = (f32x4){0.f, 0.f, 0.f, 0.f};

    // wave w stages buffer w (A0/A1/B0/B1)
    const unsigned short* gsrc =
        (wave == 0) ? A0g : (wave == 1) ? A1g : (wave == 2) ? B0g : B1g;
    const int rowbase = (wave < 2) ? bm * 128 : bn * 128;

    for (int kt = 0; kt < 32; ++kt) {
        // ---- stage: 8 issues x (64 lanes x 16B) = 8 KB per wave.
        // LDS linear slot s=q*64+lane -> (row=s>>2, kc=s&3); source column
        // pre-swizzled (kc ^ row&3) so swizzled reads land correctly (G21).
#pragma unroll
        for (int q = 0; q < 8; ++q) {
            const int slot = q * 64 + lane;
            const int row  = slot >> 2;
            const int kc   = (slot & 3) ^ (row & 3);
            const unsigned short* gp =
                gsrc + (size_t)(rowbase + row) * NN + kt * 32 + kc * 8;
            __builtin_amdgcn_global_load_lds(
                (const __attribute__((address_space(1))) void*)gp,
                (__attribute__((address_space(3))) void*)(&lds[wave][q * 512]),
                16, 0, 0);
        }
        __syncthreads();

        // ---- compute: frag loads (swizzled) + 48 MFMA
        const int c  = lane >> 4;   // k-chunk 0..3 (8 bf16 each)
        const int rA = lane & 15;
        bf16x8 a0[4], a1[4], b0[4], b1[4];
#pragma unroll
        for (int mf = 0; mf < 4; ++mf) {
            const int row = wm + mf * 16 + rA;
            const int kc  = c ^ (row & 3);
            a0[mf] = *(const bf16x8*)(&lds[0][row * 32 + kc * 8]);
            a1[mf] = *(const bf16x8*)(&lds[1][row * 32 + kc * 8]);
        }
#pragma unroll
        for (int nf = 0; nf < 4; ++nf) {
            const int row = wn + nf * 16 + rA;
            const int kc  = c ^ (row & 3);
            b0[nf] = *(const bf16x8*)(&lds[2][row * 32 + kc * 8]);
            b1[nf] = *(const bf16x8*)(&lds[3][row * 32 + kc * 8]);
        }
#pragma unroll
        for (int mf = 0; mf < 4; ++mf)
#pragma unroll
            for (int nf = 0; nf < 4; ++nf) {
                acc[mf][nf] = __builtin_amdgcn_mfma_f32_16x16x32_bf16(
                    a0[mf], b0[nf], acc[mf][nf], 0, 0, 0);
                acc[mf][nf] = __builtin_amdgcn_mfma_f32_16x16x32_bf16(
                    a0[mf], b1[nf], acc[mf][nf], 0, 0, 0);
                acc[mf][nf] = __builtin_amdgcn_mfma_f32_16x16x32_bf16(
                    a1[mf], b0[nf], acc[mf][nf], 0, 0, 0);
            }
        __syncthreads();
    }

    // epilogue: C/D layout col=lane&15, row=(lane>>4)*4+reg (guide §3)
    const int cr = lane >> 4, cc = lane & 15;
#pragma unroll
    for (int mf = 0; mf < 4; ++mf)
#pragma unroll
        for (int nf = 0; nf < 4; ++nf)
#pragma unroll
            for (int r = 0; r < 4; ++r) {
                const int row = bm * 128 + wm + mf * 16 + cr * 4 + r;
                const int col = bn * 128 + wn + nf * 16 + cc;
                H[(size_t)row * NN + col] = acc[mf][nf][r];
            }
}

// ---------------------------------------------------------------------------
// Reference-grade fp64 GEMM1 (round-3-proven) — fallback if ws too small.
// ---------------------------------------------------------------------------
#define KT 32
#define SA 132
#define SB 68
__global__ __launch_bounds__(256) void gemm1_f64(const float* __restrict__ X,
                                                 const float* __restrict__ W1,
                                                 float* __restrict__ H) {
    __shared__ float As[KT][SA];
    __shared__ float Bs[KT][SB];
    const int tid = threadIdx.x;
    const int bm  = blockIdx.y;
    const int bn  = blockIdx.x;
    const int tm  = tid >> 4;
    const int tn  = tid & 15;
    const int lrow = tid >> 3;
    const int lk4  = (tid & 7) << 2;
    double acc[8][4];
#pragma unroll
    for (int i = 0; i < 8; ++i)
#pragma unroll
        for (int j = 0; j < 4; ++j) acc[i][j] = 0.0;
    for (int kt = 0; kt < NN; kt += KT) {
#pragma unroll
        for (int p = 0; p < 4; ++p) {
            const int m = lrow + p * 32;
            const float4 v = *(const float4*)&X[(size_t)(bm * 128 + m) * NN + kt + lk4];
            As[lk4 + 0][m] = v.x; As[lk4 + 1][m] = v.y;
            As[lk4 + 2][m] = v.z; As[lk4 + 3][m] = v.w;
        }
#pragma unroll
        for (int p = 0; p < 2; ++p) {
            const int n = lrow + p * 32;
            const float4 v = *(const float4*)&W1[(size_t)(bn * 64 + n) * NN + kt + lk4];
            Bs[lk4 + 0][n] = v.x; Bs[lk4 + 1][n] = v.y;
            Bs[lk4 + 2][n] = v.z; Bs[lk4 + 3][n] = v.w;
        }
        __syncthreads();
#pragma unroll
        for (int k = 0; k < KT; ++k) {
            float a[8], b[4];
            *(float4*)&a[0] = *(const float4*)&As[k][tm * 8];
            *(float4*)&a[4] = *(const float4*)&As[k][tm * 8 + 4];
            *(float4*)&b[0] = *(const float4*)&Bs[k][tn * 4];
#pragma unroll
            for (int i = 0; i < 8; ++i)
#pragma unroll
                for (int j = 0; j < 4; ++j)
                    acc[i][j] = fma((double)a[i], (double)b[j], acc[i][j]);
        }
        __syncthreads();
    }
#pragma unroll
    for (int i = 0; i < 8; ++i) {
        float4 v;
        v.x = (float)acc[i][0]; v.y = (float)acc[i][1];
        v.z = (float)acc[i][2]; v.w = (float)acc[i][3];
        *(float4*)&H[(size_t)(bm * 128 + tm * 8 + i) * NN + bn * 64 + tn * 4] = v;
    }
}

// ---------------------------------------------------------------------------
// Transpose w2 [m][n] -> w2t [n][m]
// ---------------------------------------------------------------------------
__global__ __launch_bounds__(256) void transp_k(const float* __restrict__ A,
                                                float* __restrict__ B) {
    __shared__ float tile[32][33];
    const int tx  = threadIdx.x & 31;
    const int ty4 = (threadIdx.x >> 5) * 4;
    const int c0 = blockIdx.x * 32;
    const int r0 = blockIdx.y * 32;
#pragma unroll
    for (int i = 0; i < 4; ++i)
        tile[ty4 + i][tx] = A[(size_t)(r0 + ty4 + i) * NN + c0 + tx];
    __syncthreads();
#pragma unroll
    for (int i = 0; i < 4; ++i)
        B[(size_t)(c0 + ty4 + i) * NN + r0 + tx] = tile[tx][ty4 + i];
}

// ---------------------------------------------------------------------------
// LIF scan + borderline flagging. fp64 state; ballot -> 64-bit masks.
// Column flagged if any |hv-1| < 1e-3 (100x the max h_approx error).
// ---------------------------------------------------------------------------
__global__ __launch_bounds__(256) void lif_k(const float* __restrict__ H,
                                             unsigned long long* __restrict__ M,
                                             int* __restrict__ counter,
                                             int* __restrict__ list) {
    const int e    = blockIdx.x * 256 + threadIdx.x;  // b*1024+n
    const int lane = threadIdx.x & 63;
    const int word = e >> 6;
    double v = 0.0;
    bool flagged = false;

    float buf[8];
#pragma unroll
    for (int i = 0; i < 8; ++i) buf[i] = H[(size_t)i * 65536 + e];

#pragma unroll 8
    for (int t = 0; t < TT; ++t) {
        const float hcur = buf[t & 7];
        if (t + 8 < TT) buf[t & 7] = H[(size_t)(t + 8) * 65536 + e];
        const double hv = v + ((double)hcur - v) * 0.5;
        const bool s = (hv >= 1.0);
        flagged = flagged || (fabs(hv - 1.0) < 1e-3);
        const unsigned long long bmask = __ballot(s);
        if (lane == 0) M[(size_t)t * 1024 + word] = bmask;
        v = s ? 0.0 : hv;
    }
    if (flagged) {
        const int idx = atomicAdd(counter, 1);
        list[idx] = e;
    }
}

// ---------------------------------------------------------------------------
// Fixup: one wave per flagged column. Recompute h in fp64 from x,w1,
// redo LIF, patch mask bits atomically. Exactness guarantee for spikes.
// ---------------------------------------------------------------------------
__global__ __launch_bounds__(256) void fixup_k(const float* __restrict__ X,
                                               const float* __restrict__ W1,
                                               unsigned long long* __restrict__ M,
                                               const int* __restrict__ counter,
                                               const int* __restrict__ list) {
    const int nwaves = (gridDim.x * 256) >> 6;
    const int wid    = (blockIdx.x * 256 + threadIdx.x) >> 6;
    const int lane   = threadIdx.x & 63;
    const int count  = *counter;

    for (int j = wid; j < count; j += nwaves) {
        const int e = list[j];
        const int b = e >> 10, n = e & 1023;
        // preload this column's w1 row slice (lane covers k = lane*16..+16)
        double wk[16];
        {
            const float* wr = W1 + (size_t)n * NN + lane * 16;
#pragma unroll
            for (int i = 0; i < 16; ++i) wk[i] = (double)wr[i];
        }
        double v = 0.0;
        const unsigned long long bit = 1ull << (e & 63);
        const size_t wbase = (size_t)(e >> 6);
        for (int t = 0; t < TT; ++t) {
            const float* xr = X + ((size_t)(t * 64 + b)) * NN + lane * 16;
            double s = 0.0;
#pragma unroll
            for (int i = 0; i < 16; ++i) s = fma((double)xr[i], wk[i], s);
#pragma unroll
            for (int off = 32; off > 0; off >>= 1) s += __shfl_xor(s, off);
            const double hv = v + (s - v) * 0.5;
            const bool sp = (hv >= 1.0);
            if (lane == 0) {
                unsigned long long* mp = &M[(size_t)t * 1024 + wbase];
                if (sp) atomicOr(mp, bit);
                else    atomicAnd(mp, ~bit);
            }
            v = sp ? 0.0 : hv;
        }
    }
}

// ---------------------------------------------------------------------------
// Sparse GEMM2: out[r][:] = sum over active n of w2t[n][:]. fp64 acc.
// ---------------------------------------------------------------------------
__global__ __launch_bounds__(256) void spmm2_k(const unsigned long long* __restrict__ M,
                                               const float* __restrict__ W2T,
                                               float* __restrict__ OUT) {
    __shared__ unsigned long long sm[16];
    const int r   = blockIdx.x;
    const int tid = threadIdx.x;
    if (tid < 16) sm[tid] = M[(size_t)r * 16 + tid];
    __syncthreads();

    double a0 = 0.0, a1 = 0.0, a2 = 0.0, a3 = 0.0;
    for (int w = 0; w < 16; ++w) {
        unsigned long long bits = sm[w];
        while (bits) {
            const int l = __builtin_ctzll(bits);
            bits &= bits - 1;
            const int n = w * 64 + l;
            const float4 wv = *(const float4*)&W2T[(size_t)n * NN + tid * 4];
            a0 += (double)wv.x; a1 += (double)wv.y;
            a2 += (double)wv.z; a3 += (double)wv.w;
        }
    }
    float4 o;
    o.x = (float)a0; o.y = (float)a1; o.z = (float)a2; o.w = (float)a3;
    *(float4*)&OUT[(size_t)r * NN + tid * 4] = o;
}

// ---------------------------------------------------------------------------
extern "C" void kernel_launch(void* const* d_in, const int* in_sizes, int n_in,
                              void* d_out, int out_size, void* d_ws, size_t ws_size,
                              hipStream_t stream) {
    const float* x  = (const float*)d_in[0];
    const float* w1 = (const float*)d_in[1];
    const float* w2 = (const float*)d_in[2];
    float* out = (float*)d_out;
    char* ws = (char*)d_ws;

    // full (MFMA) layout
    const size_t oH = 0, oW2T = 33554432, oM = 37748736;
    const size_t oB0 = 38797312, oB1 = 40894464;
    const size_t oA0 = 42991616, oA1 = 59768832;
    const size_t oCnt = 76546048, oList = 76546304;
    const size_t needFull = 76808448;

    float* h   = (float*)(ws + oH);
    float* w2t = (float*)(ws + oW2T);
    unsigned long long* masks = (unsigned long long*)(ws + oM);

    if (ws_size >= needFull) {
        unsigned short* B0s = (unsigned short*)(ws + oB0);
        unsigned short* B1s = (unsigned short*)(ws + oB1);
        unsigned short* A0g = (unsigned short*)(ws + oA0);
        unsigned short* A1g = (unsigned short*)(ws + oA1);
        int* cnt  = (int*)(ws + oCnt);
        int* list = (int*)(ws + oList);

        split_k<<<8192, 256, 0, stream>>>(x, A0g, A1g);
        split_k<<<1024, 256, 0, stream>>>(w1, B0s, B1s);
        transp_k<<<dim3(32, 32), 256, 0, stream>>>(w2, w2t);
        gemm1_mfma<<<dim3(8, 64), 256, 0, stream>>>(A0g, A1g, B0s, B1s, h);
        hipMemsetAsync(cnt, 0, 4, stream);
        lif_k<<<256, 256, 0, stream>>>(h, masks, cnt, list);
        fixup_k<<<64, 256, 0, stream>>>(x, w1, masks, cnt, list);
        spmm2_k<<<8192, 256, 0, stream>>>(masks, w2t, out);
    } else {
        // fallback: round-3-proven fp64 path (ws <= 39.1 MB)
        int* cnt  = (int*)(ws + 38797312);
        int* list = (int*)(ws + 38797568);
        gemm1_f64<<<dim3(16, 64), 256, 0, stream>>>(x, w1, h);
        transp_k<<<dim3(32, 32), 256, 0, stream>>>(w2, w2t);
        hipMemsetAsync(cnt, 0, 4, stream);
        lif_k<<<256, 256, 0, stream>>>(h, masks, cnt, list);
        fixup_k<<<64, 256, 0, stream>>>(x, w1, masks, cnt, list);
        spmm2_k<<<8192, 256, 0, stream>>>(masks, w2t, out);
    }
}

// Round 5
// 145.974 us; speedup vs baseline: 3.1122x; 1.4680x over previous
//
#include <hip/hip_runtime.h>
#include <hip/hip_bf16.h>

#define TT 128
#define BB 64
#define NN 1024

typedef __attribute__((ext_vector_type(4))) float f32x4;
typedef __attribute__((ext_vector_type(8))) short bf16x8;

#define FLAG_THR 2e-4
#define MAX_FLAG 16384

// ---------------------------------------------------------------------------
// bf16 split helpers (RNE via bit trick; residual exact in fp32)
// ---------------------------------------------------------------------------
__device__ __forceinline__ unsigned short bf_hi_rne(float f, float& rem) {
    union { float f; unsigned int u; } c; c.f = f;
    const unsigned int r = c.u + 0x7fffu + ((c.u >> 16) & 1u);
    const unsigned short h = (unsigned short)(r >> 16);
    union { unsigned int u; float f; } b; b.u = ((unsigned int)h) << 16;
    rem = f - b.f;
    return h;
}

// Split x AND w1 in one launch: blocks [0,8192) -> x, [8192,9216) -> w1.
__global__ __launch_bounds__(256) void split_k(const float* __restrict__ X,
                                               unsigned short* __restrict__ XHi,
                                               unsigned short* __restrict__ XLo,
                                               const float* __restrict__ W,
                                               unsigned short* __restrict__ WHi,
                                               unsigned short* __restrict__ WLo) {
    const bool isX = blockIdx.x < 8192;
    const float* A = isX ? X : W;
    unsigned short* Hi = isX ? XHi : WHi;
    unsigned short* Lo = isX ? XLo : WLo;
    const size_t blk = isX ? blockIdx.x : (blockIdx.x - 8192);
    const size_t f = (blk * 256 + threadIdx.x) * 4;
    const float4 v = *(const float4*)(A + f);
    float r, r2;
    ushort4 hi, lo;
    hi.x = bf_hi_rne(v.x, r); lo.x = bf_hi_rne(r, r2);
    hi.y = bf_hi_rne(v.y, r); lo.y = bf_hi_rne(r, r2);
    hi.z = bf_hi_rne(v.z, r); lo.z = bf_hi_rne(r, r2);
    hi.w = bf_hi_rne(v.w, r); lo.w = bf_hi_rne(r, r2);
    *(ushort4*)(Hi + f) = hi;
    *(ushort4*)(Lo + f) = lo;
}

// ---------------------------------------------------------------------------
// GEMM1 via MFMA (proven round 4): 3-pass split-bf16, 128x128 tile, BK=32.
// ---------------------------------------------------------------------------
__global__ __launch_bounds__(256) void gemm1_mfma(
    const unsigned short* __restrict__ A0g, const unsigned short* __restrict__ A1g,
    const unsigned short* __restrict__ B0g, const unsigned short* __restrict__ B1g,
    float* __restrict__ H) {
    __shared__ unsigned short lds[4][128 * 32];

    const int tid  = threadIdx.x;
    const int wave = tid >> 6;
    const int lane = tid & 63;
    const int bm = blockIdx.y, bn = blockIdx.x;
    const int wm = (wave >> 1) * 64, wn = (wave & 1) * 64;

    f32x4 acc[4][4];
#pragma unroll
    for (int i = 0; i < 4; ++i)
#pragma unroll
        for (int j = 0; j < 4; ++j) acc[i][j] = (f32x4){0.f, 0.f, 0.f, 0.f};

    const unsigned short* gsrc =
        (wave == 0) ? A0g : (wave == 1) ? A1g : (wave == 2) ? B0g : B1g;
    const int rowbase = (wave < 2) ? bm * 128 : bn * 128;

    for (int kt = 0; kt < 32; ++kt) {
#pragma unroll
        for (int q = 0; q < 8; ++q) {
            const int slot = q * 64 + lane;
            const int row  = slot >> 2;
            const int kc   = (slot & 3) ^ (row & 3);
            const unsigned short* gp =
                gsrc + (size_t)(rowbase + row) * NN + kt * 32 + kc * 8;
            __builtin_amdgcn_global_load_lds(
                (const __attribute__((address_space(1))) void*)gp,
                (__attribute__((address_space(3))) void*)(&lds[wave][q * 512]),
                16, 0, 0);
        }
        __syncthreads();

        const int c  = lane >> 4;
        const int rA = lane & 15;
        bf16x8 a0[4], a1[4], b0[4], b1[4];
#pragma unroll
        for (int mf = 0; mf < 4; ++mf) {
            const int row = wm + mf * 16 + rA;
            const int kc  = c ^ (row & 3);
            a0[mf] = *(const bf16x8*)(&lds[0][row * 32 + kc * 8]);
            a1[mf] = *(const bf16x8*)(&lds[1][row * 32 + kc * 8]);
        }
#pragma unroll
        for (int nf = 0; nf < 4; ++nf) {
            const int row = wn + nf * 16 + rA;
            const int kc  = c ^ (row & 3);
            b0[nf] = *(const bf16x8*)(&lds[2][row * 32 + kc * 8]);
            b1[nf] = *(const bf16x8*)(&lds[3][row * 32 + kc * 8]);
        }
#pragma unroll
        for (int mf = 0; mf < 4; ++mf)
#pragma unroll
            for (int nf = 0; nf < 4; ++nf) {
                acc[mf][nf] = __builtin_amdgcn_mfma_f32_16x16x32_bf16(
                    a0[mf], b0[nf], acc[mf][nf], 0, 0, 0);
                acc[mf][nf] = __builtin_amdgcn_mfma_f32_16x16x32_bf16(
                    a0[mf], b1[nf], acc[mf][nf], 0, 0, 0);
                acc[mf][nf] = __builtin_amdgcn_mfma_f32_16x16x32_bf16(
                    a1[mf], b0[nf], acc[mf][nf], 0, 0, 0);
            }
        __syncthreads();
    }

    const int cr = lane >> 4, cc = lane & 15;
#pragma unroll
    for (int mf = 0; mf < 4; ++mf)
#pragma unroll
        for (int nf = 0; nf < 4; ++nf)
#pragma unroll
            for (int r = 0; r < 4; ++r) {
                const int row = bm * 128 + wm + mf * 16 + cr * 4 + r;
                const int col = bn * 128 + wn + nf * 16 + cc;
                H[(size_t)row * NN + col] = acc[mf][nf][r];
            }
}

// ---------------------------------------------------------------------------
// fp64 GEMM1 fallback (round-3-proven) — only if ws too small.
// ---------------------------------------------------------------------------
#define KT 32
#define SA 132
#define SB 68
__global__ __launch_bounds__(256) void gemm1_f64(const float* __restrict__ X,
                                                 const float* __restrict__ W1,
                                                 float* __restrict__ H) {
    __shared__ float As[KT][SA];
    __shared__ float Bs[KT][SB];
    const int tid = threadIdx.x;
    const int bm  = blockIdx.y;
    const int bn  = blockIdx.x;
    const int tm  = tid >> 4;
    const int tn  = tid & 15;
    const int lrow = tid >> 3;
    const int lk4  = (tid & 7) << 2;
    double acc[8][4];
#pragma unroll
    for (int i = 0; i < 8; ++i)
#pragma unroll
        for (int j = 0; j < 4; ++j) acc[i][j] = 0.0;
    for (int kt = 0; kt < NN; kt += KT) {
#pragma unroll
        for (int p = 0; p < 4; ++p) {
            const int m = lrow + p * 32;
            const float4 v = *(const float4*)&X[(size_t)(bm * 128 + m) * NN + kt + lk4];
            As[lk4 + 0][m] = v.x; As[lk4 + 1][m] = v.y;
            As[lk4 + 2][m] = v.z; As[lk4 + 3][m] = v.w;
        }
#pragma unroll
        for (int p = 0; p < 2; ++p) {
            const int n = lrow + p * 32;
            const float4 v = *(const float4*)&W1[(size_t)(bn * 64 + n) * NN + kt + lk4];
            Bs[lk4 + 0][n] = v.x; Bs[lk4 + 1][n] = v.y;
            Bs[lk4 + 2][n] = v.z; Bs[lk4 + 3][n] = v.w;
        }
        __syncthreads();
#pragma unroll
        for (int k = 0; k < KT; ++k) {
            float a[8], b[4];
            *(float4*)&a[0] = *(const float4*)&As[k][tm * 8];
            *(float4*)&a[4] = *(const float4*)&As[k][tm * 8 + 4];
            *(float4*)&b[0] = *(const float4*)&Bs[k][tn * 4];
#pragma unroll
            for (int i = 0; i < 8; ++i)
#pragma unroll
                for (int j = 0; j < 4; ++j)
                    acc[i][j] = fma((double)a[i], (double)b[j], acc[i][j]);
        }
        __syncthreads();
    }
#pragma unroll
    for (int i = 0; i < 8; ++i) {
        float4 v;
        v.x = (float)acc[i][0]; v.y = (float)acc[i][1];
        v.z = (float)acc[i][2]; v.w = (float)acc[i][3];
        *(float4*)&H[(size_t)(bm * 128 + tm * 8 + i) * NN + bn * 64 + tn * 4] = v;
    }
}

// ---------------------------------------------------------------------------
// Transpose w2 [m][n] -> w2t [n][m]
// ---------------------------------------------------------------------------
__global__ __launch_bounds__(256) void transp_k(const float* __restrict__ A,
                                                float* __restrict__ B) {
    __shared__ float tile[32][33];
    const int tx  = threadIdx.x & 31;
    const int ty4 = (threadIdx.x >> 5) * 4;
    const int c0 = blockIdx.x * 32;
    const int r0 = blockIdx.y * 32;
#pragma unroll
    for (int i = 0; i < 4; ++i)
        tile[ty4 + i][tx] = A[(size_t)(r0 + ty4 + i) * NN + c0 + tx];
    __syncthreads();
#pragma unroll
    for (int i = 0; i < 4; ++i)
        B[(size_t)(c0 + ty4 + i) * NN + r0 + tx] = tile[tx][ty4 + i];
}

// ---------------------------------------------------------------------------
// LIF scan + borderline flagging (fp64 state; ballot -> masks).
// ---------------------------------------------------------------------------
__global__ __launch_bounds__(256) void lif_k(const float* __restrict__ H,
                                             unsigned long long* __restrict__ M,
                                             int* __restrict__ counter,
                                             int* __restrict__ list) {
    const int e    = blockIdx.x * 256 + threadIdx.x;
    const int lane = threadIdx.x & 63;
    const int word = e >> 6;
    double v = 0.0;
    bool flagged = false;

    float buf[8];
#pragma unroll
    for (int i = 0; i < 8; ++i) buf[i] = H[(size_t)i * 65536 + e];

#pragma unroll 8
    for (int t = 0; t < TT; ++t) {
        const float hcur = buf[t & 7];
        if (t + 8 < TT) buf[t & 7] = H[(size_t)(t + 8) * 65536 + e];
        const double hv = v + ((double)hcur - v) * 0.5;
        const bool s = (hv >= 1.0);
        flagged = flagged || (fabs(hv - 1.0) < FLAG_THR);
        const unsigned long long bmask = __ballot(s);
        if (lane == 0) M[(size_t)t * 1024 + word] = bmask;
        v = s ? 0.0 : hv;
    }
    if (flagged) {
        const int idx = atomicAdd(counter, 1);
        if (idx < MAX_FLAG) list[idx] = e;
    }
}

// ---------------------------------------------------------------------------
// Fixup phase A: parallel fp64 dots. One wave per (flagged column, 8-t chunk).
// No serial chain -> latency fully hidden by wave parallelism.
// ---------------------------------------------------------------------------
__global__ __launch_bounds__(256) void fixup_dots_k(const float* __restrict__ X,
                                                    const float* __restrict__ W1,
                                                    const int* __restrict__ counter,
                                                    const int* __restrict__ list,
                                                    double* __restrict__ sbuf) {
    const int nw   = (gridDim.x * 256) >> 6;
    const int wid  = (blockIdx.x * 256 + threadIdx.x) >> 6;
    const int lane = threadIdx.x & 63;
    int cnt = *counter; if (cnt > MAX_FLAG) cnt = MAX_FLAG;
    const int total = cnt * 16;

    for (int item = wid; item < total; item += nw) {
        const int ci = item >> 4;
        const int tc = item & 15;
        const int e = list[ci];
        const int b = e >> 10, n = e & 1023;
        double wk[16];
        {
            const float* wr = W1 + (size_t)n * NN + lane * 16;
#pragma unroll
            for (int i = 0; i < 16; ++i) wk[i] = (double)wr[i];
        }
#pragma unroll
        for (int tt = 0; tt < 8; ++tt) {
            const int t = tc * 8 + tt;
            const float* xr = X + (size_t)(t * 64 + b) * NN + lane * 16;
            double s = 0.0;
#pragma unroll
            for (int i = 0; i < 16; ++i) s = fma((double)xr[i], wk[i], s);
#pragma unroll
            for (int off = 32; off > 0; off >>= 1) s += __shfl_xor(s, off);
            if (lane == 0) sbuf[(size_t)ci * 128 + t] = s;
        }
    }
}

// ---------------------------------------------------------------------------
// Fixup phase B: per-column LIF scan on exact dots + parallel mask patch.
// One 64-thread block per column (grid-stride).
// ---------------------------------------------------------------------------
__global__ __launch_bounds__(64) void fixup_scan_k(const double* __restrict__ sbuf,
                                                   const int* __restrict__ counter,
                                                   const int* __restrict__ list,
                                                   unsigned long long* __restrict__ M) {
    __shared__ double sv[128];
    __shared__ unsigned char sp[128];
    const int lane = threadIdx.x;
    int cnt = *counter; if (cnt > MAX_FLAG) cnt = MAX_FLAG;

    for (int ci = blockIdx.x; ci < cnt; ci += gridDim.x) {
        const int e = list[ci];
        sv[lane]      = sbuf[(size_t)ci * 128 + lane];
        sv[lane + 64] = sbuf[(size_t)ci * 128 + 64 + lane];
        __syncthreads();
        if (lane == 0) {
            double v = 0.0;
#pragma unroll
            for (int t = 0; t < TT; ++t) {
                const double hv = v + (sv[t] - v) * 0.5;
                const bool s = (hv >= 1.0);
                sp[t] = s;
                v = s ? 0.0 : hv;
            }
        }
        __syncthreads();
        const unsigned long long bit = 1ull << (e & 63);
        const size_t wbase = (size_t)(e >> 6);
#pragma unroll
        for (int p = 0; p < 2; ++p) {
            const int t = lane + p * 64;
            unsigned long long* mp = &M[(size_t)t * 1024 + wbase];
            if (sp[t]) atomicOr(mp, bit);
            else       atomicAnd(mp, ~bit);
        }
        __syncthreads();
    }
}

// ---------------------------------------------------------------------------
// Sparse GEMM2: out[r][:] = sum over active n of w2t[n][:]. fp64 acc.
// ---------------------------------------------------------------------------
__global__ __launch_bounds__(256) void spmm2_k(const unsigned long long* __restrict__ M,
                                               const float* __restrict__ W2T,
                                               float* __restrict__ OUT) {
    __shared__ unsigned long long sm[16];
    const int r   = blockIdx.x;
    const int tid = threadIdx.x;
    if (tid < 16) sm[tid] = M[(size_t)r * 16 + tid];
    __syncthreads();

    double a0 = 0.0, a1 = 0.0, a2 = 0.0, a3 = 0.0;
    for (int w = 0; w < 16; ++w) {
        unsigned long long bits = sm[w];
        while (bits) {
            const int l = __builtin_ctzll(bits);
            bits &= bits - 1;
            const int n = w * 64 + l;
            const float4 wv = *(const float4*)&W2T[(size_t)n * NN + tid * 4];
            a0 += (double)wv.x; a1 += (double)wv.y;
            a2 += (double)wv.z; a3 += (double)wv.w;
        }
    }
    float4 o;
    o.x = (float)a0; o.y = (float)a1; o.z = (float)a2; o.w = (float)a3;
    *(float4*)&OUT[(size_t)r * NN + tid * 4] = o;
}

// ---------------------------------------------------------------------------
extern "C" void kernel_launch(void* const* d_in, const int* in_sizes, int n_in,
                              void* d_out, int out_size, void* d_ws, size_t ws_size,
                              hipStream_t stream) {
    const float* x  = (const float*)d_in[0];
    const float* w1 = (const float*)d_in[1];
    const float* w2 = (const float*)d_in[2];
    float* out = (float*)d_out;
    char* ws = (char*)d_ws;

    const size_t oH = 0, oW2T = 33554432, oM = 37748736;
    const size_t oB0 = 38797312, oB1 = 40894464;
    const size_t oA0 = 42991616, oA1 = 59768832;
    const size_t oCnt = 76546048, oList = 76546304;
    const size_t needFull = 76808448;

    float* h   = (float*)(ws + oH);
    float* w2t = (float*)(ws + oW2T);
    unsigned long long* masks = (unsigned long long*)(ws + oM);

    if (ws_size >= needFull) {
        unsigned short* B0s = (unsigned short*)(ws + oB0);
        unsigned short* B1s = (unsigned short*)(ws + oB1);
        unsigned short* A0g = (unsigned short*)(ws + oA0);
        unsigned short* A1g = (unsigned short*)(ws + oA1);
        int* cnt  = (int*)(ws + oCnt);
        int* list = (int*)(ws + oList);
        // sbuf overlays A0g (x-hi): dead after gemm1_mfma; 16 MB >= MAX_FLAG*1KB
        double* sbuf = (double*)(ws + oA0);

        split_k<<<9216, 256, 0, stream>>>(x, A0g, A1g, w1, B0s, B1s);
        transp_k<<<dim3(32, 32), 256, 0, stream>>>(w2, w2t);
        gemm1_mfma<<<dim3(8, 64), 256, 0, stream>>>(A0g, A1g, B0s, B1s, h);
        hipMemsetAsync(cnt, 0, 4, stream);
        lif_k<<<256, 256, 0, stream>>>(h, masks, cnt, list);
        fixup_dots_k<<<256, 256, 0, stream>>>(x, w1, cnt, list, sbuf);
        fixup_scan_k<<<256, 64, 0, stream>>>(sbuf, cnt, list, masks);
        spmm2_k<<<8192, 256, 0, stream>>>(masks, w2t, out);
    } else {
        // fallback: fp64 GEMM1 -> h exact -> no fixup needed
        int* cnt  = (int*)(ws + 38797312);
        int* list = (int*)(ws + 38797568);
        gemm1_f64<<<dim3(16, 64), 256, 0, stream>>>(x, w1, h);
        transp_k<<<dim3(32, 32), 256, 0, stream>>>(w2, w2t);
        hipMemsetAsync(cnt, 0, 4, stream);
        lif_k<<<256, 256, 0, stream>>>(h, masks, cnt, list);
        spmm2_k<<<8192, 256, 0, stream>>>(masks, w2t, out);
    }
}

// Round 7
// 139.408 us; speedup vs baseline: 3.2588x; 1.0471x over previous
//
#include <hip/hip_runtime.h>
#include <hip/hip_bf16.h>

#define TT 128
#define BB 64
#define NN 1024

typedef __attribute__((ext_vector_type(4))) float f32x4;
typedef __attribute__((ext_vector_type(8))) short bf16x8;

#define FLAG_THR 2e-4
#define MAX_FLAG 16384

// ---------------------------------------------------------------------------
// bf16 split helpers (RNE via bit trick; residual exact in fp32)
// ---------------------------------------------------------------------------
__device__ __forceinline__ unsigned short bf_hi_rne(float f, float& rem) {
    union { float f; unsigned int u; } c; c.f = f;
    const unsigned int r = c.u + 0x7fffu + ((c.u >> 16) & 1u);
    const unsigned short h = (unsigned short)(r >> 16);
    union { unsigned int u; float f; } b; b.u = ((unsigned int)h) << 16;
    rem = f - b.f;
    return h;
}

// Fused prep kernel, block-range dispatch:
//   [0,8192)      split x  -> XHi/XLo
//   [8192,9216)   split w1 -> WHi/WLo
//   [9216,10240)  transpose w2 -> W2T
//   block 0, thread 0 additionally zeroes the flag counter.
__global__ __launch_bounds__(256) void split_k(const float* __restrict__ X,
                                               unsigned short* __restrict__ XHi,
                                               unsigned short* __restrict__ XLo,
                                               const float* __restrict__ W,
                                               unsigned short* __restrict__ WHi,
                                               unsigned short* __restrict__ WLo,
                                               const float* __restrict__ W2,
                                               float* __restrict__ W2T,
                                               int* __restrict__ cnt) {
    __shared__ float tile[32][33];
    if (blockIdx.x == 0 && threadIdx.x == 0) *cnt = 0;

    if (blockIdx.x >= 9216) {
        const int tblk = blockIdx.x - 9216;
        const int tx  = threadIdx.x & 31;
        const int ty4 = (threadIdx.x >> 5) * 4;
        const int c0 = (tblk & 31) * 32;
        const int r0 = (tblk >> 5) * 32;
#pragma unroll
        for (int i = 0; i < 4; ++i)
            tile[ty4 + i][tx] = W2[(size_t)(r0 + ty4 + i) * NN + c0 + tx];
        __syncthreads();
#pragma unroll
        for (int i = 0; i < 4; ++i)
            W2T[(size_t)(c0 + ty4 + i) * NN + r0 + tx] = tile[tx][ty4 + i];
        return;
    }

    const bool isX = blockIdx.x < 8192;
    const float* A = isX ? X : W;
    unsigned short* Hi = isX ? XHi : WHi;
    unsigned short* Lo = isX ? XLo : WLo;
    const size_t blk = isX ? blockIdx.x : (blockIdx.x - 8192);
    const size_t f = (blk * 256 + threadIdx.x) * 4;
    const float4 v = *(const float4*)(A + f);
    float r, r2;
    ushort4 hi, lo;
    hi.x = bf_hi_rne(v.x, r); lo.x = bf_hi_rne(r, r2);
    hi.y = bf_hi_rne(v.y, r); lo.y = bf_hi_rne(r, r2);
    hi.z = bf_hi_rne(v.z, r); lo.z = bf_hi_rne(r, r2);
    hi.w = bf_hi_rne(v.w, r); lo.w = bf_hi_rne(r, r2);
    *(ushort4*)(Hi + f) = hi;
    *(ushort4*)(Lo + f) = lo;
}

// ---------------------------------------------------------------------------
// GEMM1 via MFMA: 3-pass split-bf16, 128x128 tile, BK=32, 8 waves (512 thr).
// Per-wave output 64x32 (4x2 frags, 24 MFMA/K-step). Each 8KB LDS buffer is
// staged by a wave pair (4 issues each).
// global_load_lds dest = WAVE-UNIFORM base &lds[buf][(wave&1)*2048 + q*512];
// HW adds lane*16B, reproducing the proven slot*8 linear layout (r6 bug was
// a lane-varying/mis-scaled base here).
// ---------------------------------------------------------------------------
__global__ __launch_bounds__(512, 4) void gemm1_mfma(
    const unsigned short* __restrict__ A0g, const unsigned short* __restrict__ A1g,
    const unsigned short* __restrict__ B0g, const unsigned short* __restrict__ B1g,
    float* __restrict__ H) {
    __shared__ unsigned short lds[4][128 * 32];

    const int tid  = threadIdx.x;
    const int wave = tid >> 6;        // 0..7
    const int lane = tid & 63;
    const int bm = blockIdx.y, bn = blockIdx.x;
    const int wm = (wave >> 2) * 64;  // 0 / 64
    const int wn = (wave & 3) * 32;   // 0 / 32 / 64 / 96

    f32x4 acc[4][2];
#pragma unroll
    for (int i = 0; i < 4; ++i)
#pragma unroll
        for (int j = 0; j < 2; ++j) acc[i][j] = (f32x4){0.f, 0.f, 0.f, 0.f};

    const int buf = wave >> 1;
    const unsigned short* gsrc =
        (buf == 0) ? A0g : (buf == 1) ? A1g : (buf == 2) ? B0g : B1g;
    const int rowbase = (buf < 2) ? bm * 128 : bn * 128;
    const int shalf = (wave & 1) * 256;  // lane-0 slot offset within buffer

    for (int kt = 0; kt < 32; ++kt) {
        // ---- stage: 4 issues x (64 lanes x 16B) = 4 KB per wave.
#pragma unroll
        for (int q = 0; q < 4; ++q) {
            const int slot = shalf + q * 64 + lane;   // per-lane (source addr)
            const int row  = slot >> 2;
            const int kc   = (slot & 3) ^ (row & 3);
            const unsigned short* gp =
                gsrc + (size_t)(rowbase + row) * NN + kt * 32 + kc * 8;
            __builtin_amdgcn_global_load_lds(
                (const __attribute__((address_space(1))) void*)gp,
                (__attribute__((address_space(3))) void*)(
                    &lds[buf][(wave & 1) * 2048 + q * 512]),   // wave-uniform
                16, 0, 0);
        }
        __syncthreads();

        // ---- compute: frag loads (swizzled) + 24 MFMA
        const int c  = lane >> 4;
        const int rA = lane & 15;
        bf16x8 a0[4], a1[4], b0[2], b1[2];
#pragma unroll
        for (int mf = 0; mf < 4; ++mf) {
            const int row = wm + mf * 16 + rA;
            const int kc  = c ^ (row & 3);
            a0[mf] = *(const bf16x8*)(&lds[0][row * 32 + kc * 8]);
            a1[mf] = *(const bf16x8*)(&lds[1][row * 32 + kc * 8]);
        }
#pragma unroll
        for (int nf = 0; nf < 2; ++nf) {
            const int row = wn + nf * 16 + rA;
            const int kc  = c ^ (row & 3);
            b0[nf] = *(const bf16x8*)(&lds[2][row * 32 + kc * 8]);
            b1[nf] = *(const bf16x8*)(&lds[3][row * 32 + kc * 8]);
        }
#pragma unroll
        for (int mf = 0; mf < 4; ++mf)
#pragma unroll
            for (int nf = 0; nf < 2; ++nf) {
                acc[mf][nf] = __builtin_amdgcn_mfma_f32_16x16x32_bf16(
                    a0[mf], b0[nf], acc[mf][nf], 0, 0, 0);
                acc[mf][nf] = __builtin_amdgcn_mfma_f32_16x16x32_bf16(
                    a0[mf], b1[nf], acc[mf][nf], 0, 0, 0);
                acc[mf][nf] = __builtin_amdgcn_mfma_f32_16x16x32_bf16(
                    a1[mf], b0[nf], acc[mf][nf], 0, 0, 0);
            }
        __syncthreads();
    }

    const int cr = lane >> 4, cc = lane & 15;
#pragma unroll
    for (int mf = 0; mf < 4; ++mf)
#pragma unroll
        for (int nf = 0; nf < 2; ++nf)
#pragma unroll
            for (int r = 0; r < 4; ++r) {
                const int row = bm * 128 + wm + mf * 16 + cr * 4 + r;
                const int col = bn * 128 + wn + nf * 16 + cc;
                H[(size_t)row * NN + col] = acc[mf][nf][r];
            }
}

// ---------------------------------------------------------------------------
// fp64 GEMM1 fallback (round-3-proven) — only if ws too small.
// ---------------------------------------------------------------------------
#define KT 32
#define SA 132
#define SB 68
__global__ __launch_bounds__(256) void gemm1_f64(const float* __restrict__ X,
                                                 const float* __restrict__ W1,
                                                 float* __restrict__ H) {
    __shared__ float As[KT][SA];
    __shared__ float Bs[KT][SB];
    const int tid = threadIdx.x;
    const int bm  = blockIdx.y;
    const int bn  = blockIdx.x;
    const int tm  = tid >> 4;
    const int tn  = tid & 15;
    const int lrow = tid >> 3;
    const int lk4  = (tid & 7) << 2;
    double acc[8][4];
#pragma unroll
    for (int i = 0; i < 8; ++i)
#pragma unroll
        for (int j = 0; j < 4; ++j) acc[i][j] = 0.0;
    for (int kt = 0; kt < NN; kt += KT) {
#pragma unroll
        for (int p = 0; p < 4; ++p) {
            const int m = lrow + p * 32;
            const float4 v = *(const float4*)&X[(size_t)(bm * 128 + m) * NN + kt + lk4];
            As[lk4 + 0][m] = v.x; As[lk4 + 1][m] = v.y;
            As[lk4 + 2][m] = v.z; As[lk4 + 3][m] = v.w;
        }
#pragma unroll
        for (int p = 0; p < 2; ++p) {
            const int n = lrow + p * 32;
            const float4 v = *(const float4*)&W1[(size_t)(bn * 64 + n) * NN + kt + lk4];
            Bs[lk4 + 0][n] = v.x; Bs[lk4 + 1][n] = v.y;
            Bs[lk4 + 2][n] = v.z; Bs[lk4 + 3][n] = v.w;
        }
        __syncthreads();
#pragma unroll
        for (int k = 0; k < KT; ++k) {
            float a[8], b[4];
            *(float4*)&a[0] = *(const float4*)&As[k][tm * 8];
            *(float4*)&a[4] = *(const float4*)&As[k][tm * 8 + 4];
            *(float4*)&b[0] = *(const float4*)&Bs[k][tn * 4];
#pragma unroll
            for (int i = 0; i < 8; ++i)
#pragma unroll
                for (int j = 0; j < 4; ++j)
                    acc[i][j] = fma((double)a[i], (double)b[j], acc[i][j]);
        }
        __syncthreads();
    }
#pragma unroll
    for (int i = 0; i < 8; ++i) {
        float4 v;
        v.x = (float)acc[i][0]; v.y = (float)acc[i][1];
        v.z = (float)acc[i][2]; v.w = (float)acc[i][3];
        *(float4*)&H[(size_t)(bm * 128 + tm * 8 + i) * NN + bn * 64 + tn * 4] = v;
    }
}

// transpose (fallback path only)
__global__ __launch_bounds__(256) void transp_k(const float* __restrict__ A,
                                                float* __restrict__ B) {
    __shared__ float tile[32][33];
    const int tx  = threadIdx.x & 31;
    const int ty4 = (threadIdx.x >> 5) * 4;
    const int c0 = blockIdx.x * 32;
    const int r0 = blockIdx.y * 32;
#pragma unroll
    for (int i = 0; i < 4; ++i)
        tile[ty4 + i][tx] = A[(size_t)(r0 + ty4 + i) * NN + c0 + tx];
    __syncthreads();
#pragma unroll
    for (int i = 0; i < 4; ++i)
        B[(size_t)(c0 + ty4 + i) * NN + r0 + tx] = tile[tx][ty4 + i];
}

// ---------------------------------------------------------------------------
// LIF scan + borderline flagging (fp64 state; ballot -> masks).
// ---------------------------------------------------------------------------
__global__ __launch_bounds__(256) void lif_k(const float* __restrict__ H,
                                             unsigned long long* __restrict__ M,
                                             int* __restrict__ counter,
                                             int* __restrict__ list) {
    const int e    = blockIdx.x * 256 + threadIdx.x;
    const int lane = threadIdx.x & 63;
    const int word = e >> 6;
    double v = 0.0;
    bool flagged = false;

    float buf[8];
#pragma unroll
    for (int i = 0; i < 8; ++i) buf[i] = H[(size_t)i * 65536 + e];

#pragma unroll 8
    for (int t = 0; t < TT; ++t) {
        const float hcur = buf[t & 7];
        if (t + 8 < TT) buf[t & 7] = H[(size_t)(t + 8) * 65536 + e];
        const double hv = v + ((double)hcur - v) * 0.5;
        const bool s = (hv >= 1.0);
        flagged = flagged || (fabs(hv - 1.0) < FLAG_THR);
        const unsigned long long bmask = __ballot(s);
        if (lane == 0) M[(size_t)t * 1024 + word] = bmask;
        v = s ? 0.0 : hv;
    }
    if (flagged) {
        const int idx = atomicAdd(counter, 1);
        if (idx < MAX_FLAG) list[idx] = e;
    }
}

// ---------------------------------------------------------------------------
// Fixup phase A: parallel fp64 dots, one wave per (flagged column, 8-t chunk).
// ---------------------------------------------------------------------------
__global__ __launch_bounds__(256) void fixup_dots_k(const float* __restrict__ X,
                                                    const float* __restrict__ W1,
                                                    const int* __restrict__ counter,
                                                    const int* __restrict__ list,
                                                    double* __restrict__ sbuf) {
    const int nw   = (gridDim.x * 256) >> 6;
    const int wid  = (blockIdx.x * 256 + threadIdx.x) >> 6;
    const int lane = threadIdx.x & 63;
    int cnt = *counter; if (cnt > MAX_FLAG) cnt = MAX_FLAG;
    const int total = cnt * 16;

    for (int item = wid; item < total; item += nw) {
        const int ci = item >> 4;
        const int tc = item & 15;
        const int e = list[ci];
        const int b = e >> 10, n = e & 1023;
        double wk[16];
        {
            const float* wr = W1 + (size_t)n * NN + lane * 16;
#pragma unroll
            for (int i = 0; i < 16; ++i) wk[i] = (double)wr[i];
        }
#pragma unroll
        for (int tt = 0; tt < 8; ++tt) {
            const int t = tc * 8 + tt;
            const float* xr = X + (size_t)(t * 64 + b) * NN + lane * 16;
            double s = 0.0;
#pragma unroll
            for (int i = 0; i < 16; ++i) s = fma((double)xr[i], wk[i], s);
#pragma unroll
            for (int off = 32; off > 0; off >>= 1) s += __shfl_xor(s, off);
            if (lane == 0) sbuf[(size_t)ci * 128 + t] = s;
        }
    }
}

// ---------------------------------------------------------------------------
// Fixup phase B: per-column LIF scan on exact dots + parallel mask patch.
// ---------------------------------------------------------------------------
__global__ __launch_bounds__(64) void fixup_scan_k(const double* __restrict__ sbuf,
                                                   const int* __restrict__ counter,
                                                   const int* __restrict__ list,
                                                   unsigned long long* __restrict__ M) {
    __shared__ double sv[128];
    __shared__ unsigned char sp[128];
    const int lane = threadIdx.x;
    int cnt = *counter; if (cnt > MAX_FLAG) cnt = MAX_FLAG;

    for (int ci = blockIdx.x; ci < cnt; ci += gridDim.x) {
        const int e = list[ci];
        sv[lane]      = sbuf[(size_t)ci * 128 + lane];
        sv[lane + 64] = sbuf[(size_t)ci * 128 + 64 + lane];
        __syncthreads();
        if (lane == 0) {
            double v = 0.0;
#pragma unroll
            for (int t = 0; t < TT; ++t) {
                const double hv = v + (sv[t] - v) * 0.5;
                const bool s = (hv >= 1.0);
                sp[t] = s;
                v = s ? 0.0 : hv;
            }
        }
        __syncthreads();
        const unsigned long long bit = 1ull << (e & 63);
        const size_t wbase = (size_t)(e >> 6);
#pragma unroll
        for (int p = 0; p < 2; ++p) {
            const int t = lane + p * 64;
            unsigned long long* mp = &M[(size_t)t * 1024 + wbase];
            if (sp[t]) atomicOr(mp, bit);
            else       atomicAnd(mp, ~bit);
        }
        __syncthreads();
    }
}

// ---------------------------------------------------------------------------
// Sparse GEMM2: out[r][:] = sum over active n of w2t[n][:]. fp64 acc.
// ---------------------------------------------------------------------------
__global__ __launch_bounds__(256) void spmm2_k(const unsigned long long* __restrict__ M,
                                               const float* __restrict__ W2T,
                                               float* __restrict__ OUT) {
    __shared__ unsigned long long sm[16];
    const int r   = blockIdx.x;
    const int tid = threadIdx.x;
    if (tid < 16) sm[tid] = M[(size_t)r * 16 + tid];
    __syncthreads();

    double a0 = 0.0, a1 = 0.0, a2 = 0.0, a3 = 0.0;
    for (int w = 0; w < 16; ++w) {
        unsigned long long bits = sm[w];
        while (bits) {
            const int l = __builtin_ctzll(bits);
            bits &= bits - 1;
            const int n = w * 64 + l;
            const float4 wv = *(const float4*)&W2T[(size_t)n * NN + tid * 4];
            a0 += (double)wv.x; a1 += (double)wv.y;
            a2 += (double)wv.z; a3 += (double)wv.w;
        }
    }
    float4 o;
    o.x = (float)a0; o.y = (float)a1; o.z = (float)a2; o.w = (float)a3;
    *(float4*)&OUT[(size_t)r * NN + tid * 4] = o;
}

// ---------------------------------------------------------------------------
extern "C" void kernel_launch(void* const* d_in, const int* in_sizes, int n_in,
                              void* d_out, int out_size, void* d_ws, size_t ws_size,
                              hipStream_t stream) {
    const float* x  = (const float*)d_in[0];
    const float* w1 = (const float*)d_in[1];
    const float* w2 = (const float*)d_in[2];
    float* out = (float*)d_out;
    char* ws = (char*)d_ws;

    const size_t oH = 0, oW2T = 33554432, oM = 37748736;
    const size_t oB0 = 38797312, oB1 = 40894464;
    const size_t oA0 = 42991616, oA1 = 59768832;
    const size_t oCnt = 76546048, oList = 76546304;
    const size_t needFull = 76808448;

    float* h   = (float*)(ws + oH);
    float* w2t = (float*)(ws + oW2T);
    unsigned long long* masks = (unsigned long long*)(ws + oM);

    if (ws_size >= needFull) {
        unsigned short* B0s = (unsigned short*)(ws + oB0);
        unsigned short* B1s = (unsigned short*)(ws + oB1);
        unsigned short* A0g = (unsigned short*)(ws + oA0);
        unsigned short* A1g = (unsigned short*)(ws + oA1);
        int* cnt  = (int*)(ws + oCnt);
        int* list = (int*)(ws + oList);
        double* sbuf = (double*)(ws + oA0);  // overlays A0g (dead after gemm)

        split_k<<<10240, 256, 0, stream>>>(x, A0g, A1g, w1, B0s, B1s, w2, w2t, cnt);
        gemm1_mfma<<<dim3(8, 64), 512, 0, stream>>>(A0g, A1g, B0s, B1s, h);
        lif_k<<<256, 256, 0, stream>>>(h, masks, cnt, list);
        fixup_dots_k<<<256, 256, 0, stream>>>(x, w1, cnt, list, sbuf);
        fixup_scan_k<<<256, 64, 0, stream>>>(sbuf, cnt, list, masks);
        spmm2_k<<<8192, 256, 0, stream>>>(masks, w2t, out);
    } else {
        // fallback: fp64 GEMM1 -> h exact -> no fixup needed
        int* cnt  = (int*)(ws + 38797312);
        int* list = (int*)(ws + 38797568);
        gemm1_f64<<<dim3(16, 64), 256, 0, stream>>>(x, w1, h);
        transp_k<<<dim3(32, 32), 256, 0, stream>>>(w2, w2t);
        hipMemsetAsync(cnt, 0, 4, stream);
        lif_k<<<256, 256, 0, stream>>>(h, masks, cnt, list);
        spmm2_k<<<8192, 256, 0, stream>>>(masks, w2t, out);
    }
}